// Round 1
// baseline (183.969 us; speedup 1.0000x reference)
//
#include <hip/hip_runtime.h>

#define Hdim 128
#define Wdim 128
#define Cdim 64
#define Bdim 4
#define NPIX (Bdim * Hdim * Wdim)   // 65536

// ---------------------------------------------------------------------------
// Kernel 1: offset = pointwise(p_pw) . depthwise3x3(p_dw) applied to x
// One thread per pixel (b,h,w); 18 output channels accumulated in registers.
// ---------------------------------------------------------------------------
__global__ __launch_bounds__(256) void offset_kernel(
    const float* __restrict__ x,     // (B, C, H, W)
    const float* __restrict__ p_dw,  // (C, 1, 3, 3)
    const float* __restrict__ p_pw,  // (18, C, 1, 1)
    float* __restrict__ off)         // (NPIX, 18)  pixel-major
{
    int tid = blockIdx.x * blockDim.x + threadIdx.x;
    if (tid >= NPIX) return;
    int w = tid & (Wdim - 1);
    int h = (tid >> 7) & (Hdim - 1);
    int b = tid >> 14;

    float acc[18];
#pragma unroll
    for (int j = 0; j < 18; ++j) acc[j] = 0.f;

    for (int c = 0; c < Cdim; ++c) {
        const float* xb = x + ((size_t)(b * Cdim + c) * Hdim) * Wdim;
        float t = 0.f;
#pragma unroll
        for (int dh = -1; dh <= 1; ++dh) {
            int hh = h + dh;
            bool okh = (hh >= 0) & (hh < Hdim);
#pragma unroll
            for (int dw = -1; dw <= 1; ++dw) {
                int ww = w + dw;
                bool ok = okh & (ww >= 0) & (ww < Wdim);
                float v = ok ? xb[hh * Wdim + ww] : 0.f;
                t += v * p_dw[c * 9 + (dh + 1) * 3 + (dw + 1)];
            }
        }
#pragma unroll
        for (int j = 0; j < 18; ++j)
            acc[j] += p_pw[j * Cdim + c] * t;
    }

    float* o = off + (size_t)tid * 18;
#pragma unroll
    for (int j = 0; j < 18; ++j) o[j] = acc[j];
}

// ---------------------------------------------------------------------------
// Kernel 2: deformable bilinear sampling + collapsed stride-3 depthwise (c_dw)
// + pointwise (c_pw).  One thread per pixel; per-k sampling geometry computed
// once and shared across all 64 channels; pad-zero handled by folding a
// validity mask into the bilinear weights (indices clamped in-bounds).
// ---------------------------------------------------------------------------
__global__ __launch_bounds__(256) void deform_kernel(
    const float* __restrict__ x,     // (B, C, H, W)
    const float* __restrict__ c_dw,  // (C, 1, 3, 3)
    const float* __restrict__ c_pw,  // (C, C, 1, 1)
    const float* __restrict__ off,   // (NPIX, 18)
    float* __restrict__ out)         // (B, C, H, W)
{
    int tid = blockIdx.x * blockDim.x + threadIdx.x;
    if (tid >= NPIX) return;
    int w = tid & (Wdim - 1);
    int h = (tid >> 7) & (Hdim - 1);
    int b = tid >> 14;

    const float* o = off + (size_t)tid * 18;
    const float* xbase = x + (size_t)b * Cdim * Hdim * Wdim;

    float acc[Cdim];
#pragma unroll
    for (int c = 0; c < Cdim; ++c) acc[c] = 0.f;

    for (int k = 0; k < 9; ++k) {
        // p = p0 + p_n + offset   (padded coords, Hp=Wp=130)
        float px = (float)(h + 1) + (float)(k / 3 - 1) + o[k];
        float py = (float)(w + 1) + (float)(k % 3 - 1) + o[k + 9];

        float fx = floorf(px), fy = floorf(py);
        float ltx = fminf(fmaxf(fx, 0.f), 129.f);
        float lty = fminf(fmaxf(fy, 0.f), 129.f);
        float rbx = fminf(fmaxf(fx + 1.f, 0.f), 129.f);
        float rby = fminf(fmaxf(fy + 1.f, 0.f), 129.f);
        float pxc = fminf(fmaxf(px, 0.f), 129.f);
        float pyc = fminf(fmaxf(py, 0.f), 129.f);

        float glt = (1.f + ltx - pxc) * (1.f + lty - pyc);
        float grb = (1.f - rbx + pxc) * (1.f - rby + pyc);
        float glb = (1.f + ltx - pxc) * (1.f - rby + pyc);
        float grt = (1.f - rbx + pxc) * (1.f + lty - pyc);

        int ix0 = (int)ltx, iy0 = (int)lty, ix1 = (int)rbx, iy1 = (int)rby;
        // padded coord q maps to x coord q-1; nonzero only when 1<=q<=128
        float mx0 = (ix0 >= 1 && ix0 <= Hdim) ? 1.f : 0.f;
        float my0 = (iy0 >= 1 && iy0 <= Wdim) ? 1.f : 0.f;
        float mx1 = (ix1 >= 1 && ix1 <= Hdim) ? 1.f : 0.f;
        float my1 = (iy1 >= 1 && iy1 <= Wdim) ? 1.f : 0.f;
        // fold pad-zero mask into weights, clamp indices in-bounds
        glt *= mx0 * my0;
        grb *= mx1 * my1;
        glb *= mx0 * my1;
        grt *= mx1 * my0;
        int cx0 = min(max(ix0 - 1, 0), Hdim - 1);
        int cy0 = min(max(iy0 - 1, 0), Wdim - 1);
        int cx1 = min(max(ix1 - 1, 0), Hdim - 1);
        int cy1 = min(max(iy1 - 1, 0), Wdim - 1);
        int i00 = cx0 * Wdim + cy0;   // lt  (ltx,lty)
        int i11 = cx1 * Wdim + cy1;   // rb  (rbx,rby)
        int i01 = cx0 * Wdim + cy1;   // lb  (ltx,rby)
        int i10 = cx1 * Wdim + cy0;   // rt  (rbx,lty)

#pragma unroll
        for (int c = 0; c < Cdim; ++c) {
            const float* xb = xbase + (size_t)c * Hdim * Wdim;
            float s = glt * xb[i00] + grb * xb[i11]
                    + glb * xb[i01] + grt * xb[i10];
            acc[c] += c_dw[c * 9 + k] * s;
        }
    }

    // pointwise: out[b,oc,h,w] = sum_c c_pw[oc,c] * acc[c]
    size_t obase = ((size_t)b * Cdim * Hdim + h) * Wdim + w;
    for (int oc = 0; oc < Cdim; ++oc) {
        float s = 0.f;
#pragma unroll
        for (int c = 0; c < Cdim; ++c)
            s += c_pw[oc * Cdim + c] * acc[c];
        out[obase + (size_t)oc * Hdim * Wdim] = s;
    }
}

extern "C" void kernel_launch(void* const* d_in, const int* in_sizes, int n_in,
                              void* d_out, int out_size, void* d_ws, size_t ws_size,
                              hipStream_t stream) {
    const float* x    = (const float*)d_in[0];
    const float* p_dw = (const float*)d_in[1];
    const float* p_pw = (const float*)d_in[2];
    const float* c_dw = (const float*)d_in[3];
    const float* c_pw = (const float*)d_in[4];
    float* out = (float*)d_out;
    float* off = (float*)d_ws;   // NPIX * 18 floats = 4.72 MB

    dim3 blk(256);
    dim3 grd(NPIX / 256);
    offset_kernel<<<grd, blk, 0, stream>>>(x, p_dw, p_pw, off);
    deform_kernel<<<grd, blk, 0, stream>>>(x, c_dw, c_pw, off, out);
}